// Round 16
// baseline (216.829 us; speedup 1.0000x reference)
//
#include <hip/hip_runtime.h>
#include <hip/hip_bf16.h>

#define EMBED 256
#define HEADS 8
#define BATCH 8
#define SEQ   1024
#define NROWS 8192

typedef __attribute__((ext_vector_type(8))) _Float16 half8;   // 8 fp16
typedef __attribute__((ext_vector_type(4))) float f32x4;
typedef unsigned int  uint;
typedef unsigned short ushort;

#define QE   ((size_t)2097152)   /* per-head elems: 8192*256 */

__device__ __forceinline__ ushort f2h(float f) {
    union { _Float16 h; ushort u; } cv; cv.h = (_Float16)f; return cv.u;
}

// ---------------------------------------------------------------------------
// K0: fp32 -> fp16 convert for X and all weights, one launch.
// ---------------------------------------------------------------------------
__global__ __launch_bounds__(256) void convert_f16(
    const float* __restrict__ X,  const float* __restrict__ Wq,
    const float* __restrict__ Wk, const float* __restrict__ Wv,
    const float* __restrict__ Wo,
    ushort* __restrict__ Xf, ushort* __restrict__ Wqkf,
    ushort* __restrict__ Wvf, ushort* __restrict__ Wof)
{
    const int blk = blockIdx.x;
    const float* src; ushort* dst; int i;
    if (blk < 2048)      { src = X;  dst = Xf;            i = blk * 256 + threadIdx.x; }
    else if (blk < 2560) { src = Wq; dst = Wqkf;          i = (blk - 2048) * 256 + threadIdx.x; }
    else if (blk < 3072) { src = Wk; dst = Wqkf + 524288; i = (blk - 2560) * 256 + threadIdx.x; }
    else if (blk < 3584) { src = Wv; dst = Wvf;           i = (blk - 3072) * 256 + threadIdx.x; }
    else                 { src = Wo; dst = Wof;           i = (blk - 3584) * 256 + threadIdx.x; }
    const float4 v = ((const float4*)src)[i];
    uint2 P;
    P.x = (uint)f2h(v.x) | ((uint)f2h(v.y) << 16);
    P.y = (uint)f2h(v.z) | ((uint)f2h(v.w) << 16);
    ((uint2*)dst)[i] = P;
}

// ---------------------------------------------------------------------------
// Single-pass fp16 MFMA GEMM core (NT): BM=BN=128, BK=64, KD=256,
// 256 threads = 4 waves (2x2), serial staging (R14-proven).
// mode 0: q/k write; mode 1: vt write.
// ---------------------------------------------------------------------------
__device__ __forceinline__ void gemm1p_core(
    const ushort* __restrict__ Ag, const ushort* __restrict__ Bg,
    ushort* __restrict__ o0, ushort* __restrict__ o1,
    ushort* Ah, ushort* Bh, int m0, int n0, int mode)
{
    const int tid = threadIdx.x, w = tid >> 6, l = tid & 63;
    const int wr = w >> 1, wc = w & 1, g = l >> 4, c16 = l & 15;
    const int sr = l >> 3, sb = l & 7;

    f32x4 acc[4][4];
#pragma unroll
    for (int mi = 0; mi < 4; ++mi)
#pragma unroll
        for (int ni = 0; ni < 4; ++ni) acc[mi][ni] = (f32x4){0.f, 0.f, 0.f, 0.f};

    for (int k0 = 0; k0 < 256; k0 += 64) {
        __syncthreads();
#pragma unroll
        for (int j = 0; j < 4; ++j) {
            const int rb = w * 32 + j * 8;
            const int r  = rb + sr;
            const size_t srcA = (size_t)(m0 + r) * 256 + k0 + ((sb ^ (r & 7)) * 8);
            __builtin_amdgcn_global_load_lds(Ag + srcA, &Ah[rb * 64], 16, 0, 0);
            const size_t srcB = (size_t)(n0 + r) * 256 + k0 + ((sb ^ (r & 7)) * 8);
            __builtin_amdgcn_global_load_lds(Bg + srcB, &Bh[rb * 64], 16, 0, 0);
        }
        asm volatile("s_waitcnt vmcnt(0)" ::: "memory");
        __syncthreads();

#pragma unroll
        for (int kh = 0; kh < 2; ++kh) {
            const int bsel = ((kh << 2) | g) ^ (c16 & 7);
            half8 af[4], bf[4];
#pragma unroll
            for (int mi = 0; mi < 4; ++mi)
                af[mi] = *(const half8*)&Ah[(wr * 64 + mi * 16 + c16) * 64 + bsel * 8];
#pragma unroll
            for (int ni = 0; ni < 4; ++ni)
                bf[ni] = *(const half8*)&Bh[(wc * 64 + ni * 16 + c16) * 64 + bsel * 8];
#pragma unroll
            for (int mi = 0; mi < 4; ++mi)
#pragma unroll
                for (int ni = 0; ni < 4; ++ni)
                    acc[mi][ni] = __builtin_amdgcn_mfma_f32_16x16x32_f16(af[mi], bf[ni], acc[mi][ni], 0, 0, 0);
        }
    }

#pragma unroll
    for (int mi = 0; mi < 4; ++mi)
#pragma unroll
        for (int ni = 0; ni < 4; ++ni) {
            const int n = n0 + wc * 64 + ni * 16 + c16;
            if (mode == 0) {
                const int op = n >> 11, hh = (n >> 8) & 7, d = n & 255;
                ushort* tq = (op ? o1 : o0) + (size_t)hh * QE + d;
#pragma unroll
                for (int j = 0; j < 4; ++j) {
                    const int m = m0 + wr * 64 + mi * 16 + 4 * g + j;
                    tq[(size_t)m * 256] = f2h(acc[mi][ni][j]);
                }
            } else {
#pragma unroll
                for (int j = 0; j < 4; ++j) {
                    const int m = m0 + wr * 64 + mi * 16 + 4 * g + j;
                    o0[(size_t)m * NROWS + n] = f2h(acc[mi][ni][j]);
                }
            }
        }
}

// Merged QK + VT projection launch: bid<2048 -> qk GEMM, else vt GEMM.
// vt part: n is the XCD-partitioned dim (X footprint 512KB + Wv 1MB per XCD).
__global__ __launch_bounds__(256) void gemm_qkvt(
    const ushort* __restrict__ Xf,
    const ushort* __restrict__ Wqkf, const ushort* __restrict__ Wvf,
    ushort* __restrict__ qf, ushort* __restrict__ kf, ushort* __restrict__ vtb)
{
    __shared__ __align__(16) ushort Ah[128 * 64];
    __shared__ __align__(16) ushort Bh[128 * 64];
    const int bid = blockIdx.x;
    if (bid < 2048) {
        const int wg = (bid & 7) * 256 + (bid >> 3);
        gemm1p_core(Xf, Wqkf, qf, kf, Ah, Bh, (wg >> 5) * 128, (wg & 31) * 128, 0);
    } else {
        const int b2 = bid - 2048;
        const int wg = (b2 & 7) * 128 + (b2 >> 3);
        gemm1p_core(Wvf, Xf, vtb, nullptr, Ah, Bh, (wg & 15) * 128, (wg >> 4) * 128, 1);
    }
}

// ---------------------------------------------------------------------------
// K3: fp16 output projection, BM=64 x BN=64 -> 512 blocks, serial staging.
// out[8192][256] = ocf x Wof^T + bo. LDS 16KB.
// ---------------------------------------------------------------------------
__global__ __launch_bounds__(256) void gemm_out_f16(
    const ushort* __restrict__ A, const ushort* __restrict__ Bw,
    const float* __restrict__ bias, float* __restrict__ fo)
{
    __shared__ __align__(16) ushort Ah[64 * 64];
    __shared__ __align__(16) ushort Bh[64 * 64];

    const int wg = (blockIdx.x & 7) * 64 + (blockIdx.x >> 3);
    const int m0 = (wg >> 2) * 64;
    const int n0 = (wg & 3) * 64;

    const int tid = threadIdx.x, w = tid >> 6, l = tid & 63;
    const int wr = w >> 1, wc = w & 1, g = l >> 4, c16 = l & 15;
    const int sr = l >> 3, sb = l & 7;

    f32x4 acc[2][2];
#pragma unroll
    for (int mi = 0; mi < 2; ++mi)
#pragma unroll
        for (int ni = 0; ni < 2; ++ni) acc[mi][ni] = (f32x4){0.f, 0.f, 0.f, 0.f};

    for (int k0 = 0; k0 < 2048; k0 += 64) {
        __syncthreads();
#pragma unroll
        for (int j = 0; j < 2; ++j) {
            const int rb = w * 16 + j * 8;
            const int r  = rb + sr;
            const size_t srcA = (size_t)(m0 + r) * 2048 + k0 + ((sb ^ (r & 7)) * 8);
            __builtin_amdgcn_global_load_lds(A + srcA, &Ah[rb * 64], 16, 0, 0);
            const size_t srcB = (size_t)(n0 + r) * 2048 + k0 + ((sb ^ (r & 7)) * 8);
            __builtin_amdgcn_global_load_lds(Bw + srcB, &Bh[rb * 64], 16, 0, 0);
        }
        asm volatile("s_waitcnt vmcnt(0)" ::: "memory");
        __syncthreads();

#pragma unroll
        for (int kh = 0; kh < 2; ++kh) {
            const int bsel = ((kh << 2) | g) ^ (c16 & 7);
            half8 af[2], bf[2];
#pragma unroll
            for (int mi = 0; mi < 2; ++mi)
                af[mi] = *(const half8*)&Ah[(wr * 32 + mi * 16 + c16) * 64 + bsel * 8];
#pragma unroll
            for (int ni = 0; ni < 2; ++ni)
                bf[ni] = *(const half8*)&Bh[(wc * 32 + ni * 16 + c16) * 64 + bsel * 8];
#pragma unroll
            for (int mi = 0; mi < 2; ++mi)
#pragma unroll
                for (int ni = 0; ni < 2; ++ni)
                    acc[mi][ni] = __builtin_amdgcn_mfma_f32_16x16x32_f16(af[mi], bf[ni], acc[mi][ni], 0, 0, 0);
        }
    }

#pragma unroll
    for (int mi = 0; mi < 2; ++mi)
#pragma unroll
        for (int ni = 0; ni < 2; ++ni) {
            const int n = n0 + wc * 32 + ni * 16 + c16;
            const float bb = bias[n];
#pragma unroll
            for (int j = 0; j < 4; ++j) {
                const int m = m0 + wr * 32 + mi * 16 + 4 * g + j;
                fo[(size_t)m * 256 + n] = acc[mi][ni][j] + bb;
            }
        }
}

// ---------------------------------------------------------------------------
// K2: fp16 MFMA flash attention — V-DIRECT build.
// VT LDS tile removed: each wave loads its V fragments straight from global
// (4 batches of 4 dwordx4, one batch ahead; L2-served, 16 same-(h,b) blocks
// pinned per XCD). LDS 36KB = K dbuf 32K + P 4K -> one barrier per k-tile
// (K staging only; P-bounce is per-wave). 16 q/wave, 1024 blocks heavy-first.
// LDS reads/wave-ktile: 33 -> 17.
// ---------------------------------------------------------------------------
__global__ __launch_bounds__(256, 3) void flash_mfma(
    const ushort* __restrict__ qf, const ushort* __restrict__ kf,
    const ushort* __restrict__ vt, ushort* __restrict__ ocf)
{
    __shared__ __align__(16) ushort Ks[2][32 * 256];
    __shared__ __align__(16) ushort Pls[4][512];

    const int bid = blockIdx.x;
    const int idx = bid >> 3;
    const int hb  = (bid & 7) * 8 + (idx & 7);   // same-XCD hb groups
    const int qst = 15 - (idx >> 3);             // heavy-first
    const int h = hb >> 3, b = hb & 7;

    const int tid = threadIdx.x;
    const int w = tid >> 6, l = tid & 63;
    const int g = l >> 4, c16 = l & 15;
    const size_t qk_base = (size_t)h * QE + (size_t)b * (SEQ * EMBED);
    const size_t vt_base = (size_t)h * QE + (size_t)b * SEQ;

    const int psw = (c16 >> 1) & 3;
    const int rsw = c16 & 7;
    const int qw0 = qst * 64 + w * 16;
    const int q0 = qw0 + c16;

    half8 qfr[8];
    {
        const ushort* qr = qf + qk_base + (size_t)q0 * EMBED + g * 8;
#pragma unroll
        for (int kc = 0; kc < 8; ++kc)
            qfr[kc] = *(const half8*)(qr + kc * 32);
    }

    const ushort* kbase = kf + qk_base;
    // V per-lane fragment base: frag dt reads vt[vt_base + (dt*16+c16)*NROWS + kt*32 + g*8]
    const ushort* vbl = vt + vt_base + (size_t)c16 * NROWS + g * 8;

    const int krow_l = l >> 5, kblk = l & 31;
    uint koff[4];
#pragma unroll
    for (int j = 0; j < 4; ++j) {
        const int row = 8 * w + 2 * j + krow_l;
        koff[j] = (uint)(row * EMBED + ((kblk ^ (row & 7)) * 8));
    }

    f32x4 acc[16];
#pragma unroll
    for (int dt = 0; dt < 16; ++dt) acc[dt] = (f32x4){0.f, 0.f, 0.f, 0.f};
    float m_r = -1e30f, l_p = 0.f;

    char* pw = (char*)&Pls[w][0];
    const int nkt = 2 * qst + 2;

    // prologue: stage K[0]
#pragma unroll
    for (int j = 0; j < 4; ++j)
        __builtin_amdgcn_global_load_lds(kbase + koff[j], &Ks[0][(8 * w + 2 * j) * 256], 16, 0, 0);
    asm volatile("s_waitcnt vmcnt(0)" ::: "memory");
    __builtin_amdgcn_s_barrier();
    __builtin_amdgcn_sched_barrier(0);

    for (int kt = 0; kt < nkt; ++kt) {
        // issue K[kt+1] staging (lands by the barrier at iter end)
        const bool havek = (kt + 1 < nkt);
        if (havek) {
            const ushort* kb = kbase + (size_t)(kt + 1) * (32 * EMBED);
#pragma unroll
            for (int j = 0; j < 4; ++j)
                __builtin_amdgcn_global_load_lds(kb + koff[j],
                                                 &Ks[(kt + 1) & 1][(8 * w + 2 * j) * 256], 16, 0, 0);
        }

        const bool active = (kt * 32 <= qw0 + 15);
        if (active) {
            const ushort* vkt = vbl + kt * 32;
            // V batch A (dt 0..3) issued early: latency hides under QK+softmax
            half8 vfA0 = *(const half8*)(vkt + (size_t)0 * (16 * NROWS));
            half8 vfA1 = *(const half8*)(vkt + (size_t)1 * (16 * NROWS));
            half8 vfA2 = *(const half8*)(vkt + (size_t)2 * (16 * NROWS));
            half8 vfA3 = *(const half8*)(vkt + (size_t)3 * (16 * NROWS));

            // ---- QK^T on K[kt] (complete since previous barrier) ----
            const ushort* Kb = &Ks[kt & 1][0];
            f32x4 s0 = (f32x4){0.f, 0.f, 0.f, 0.f};
            f32x4 s1 = (f32x4){0.f, 0.f, 0.f, 0.f};
#pragma unroll
            for (int kc = 0; kc < 8; ++kc) {
                const int blk = ((kc * 4 + g) ^ rsw) * 8;
                const half8 a0 = *(const half8*)&Kb[c16 * 256 + blk];
                const half8 a1 = *(const half8*)&Kb[(c16 + 16) * 256 + blk];
                s0 = __builtin_amdgcn_mfma_f32_16x16x32_f16(a0, qfr[kc], s0, 0, 0, 0);
                s1 = __builtin_amdgcn_mfma_f32_16x16x32_f16(a1, qfr[kc], s1, 0, 0, 0);
            }
            const int k0b = kt * 32 + 4 * g;
            float p0[4], p1[4];
            float pm = -1e30f;
#pragma unroll
            for (int r = 0; r < 4; ++r) {
                p0[r] = (k0b + r      > q0) ? -1e30f : s0[r];
                p1[r] = (k0b + 16 + r > q0) ? -1e30f : s1[r];
                pm = fmaxf(pm, fmaxf(p0[r], p1[r]));
            }
            if (__any(pm > m_r + 8.f)) {
                float gm = fmaxf(pm, __shfl_xor(pm, 16));
                gm = fmaxf(gm, __shfl_xor(gm, 32));
                const float mn = fmaxf(m_r, gm);
                const float sc = __expf(m_r - mn);
                l_p *= sc;
#pragma unroll
                for (int dt = 0; dt < 16; ++dt) acc[dt] *= sc;
                m_r = mn;
            }
#pragma unroll
            for (int r = 0; r < 4; ++r) {
                p0[r] = __expf(p0[r] - m_r);
                p1[r] = __expf(p1[r] - m_r);
                l_p += p0[r] + p1[r];
            }
            // ---- P bounce (per-wave LDS; compiler orders write->read) ----
#pragma unroll
            for (int t = 0; t < 2; ++t)
#pragma unroll
                for (int u = 0; u < 2; ++u) {
                    const int kk = 16 * t + 4 * g + 2 * u;
                    const int off = c16 * 64 + (((kk >> 3) ^ psw) * 16) + (kk & 7) * 2;
                    const float lo = t ? p1[2 * u] : p0[2 * u];
                    const float hi = t ? p1[2 * u + 1] : p0[2 * u + 1];
                    *(uint*)(pw + off) = (uint)f2h(lo) | ((uint)f2h(hi) << 16);
                }
            const half8 pfrag = *(const half8*)(pw + c16 * 64 + ((g ^ psw) * 16));

            // ---- PV: 4 batches of 4, one batch of loads ahead ----
            half8 vfB0 = *(const half8*)(vkt + (size_t)4 * (16 * NROWS));
            half8 vfB1 = *(const half8*)(vkt + (size_t)5 * (16 * NROWS));
            half8 vfB2 = *(const half8*)(vkt + (size_t)6 * (16 * NROWS));
            half8 vfB3 = *(const half8*)(vkt + (size_t)7 * (16 * NROWS));
            acc[0] = __builtin_amdgcn_mfma_f32_16x16x32_f16(vfA0, pfrag, acc[0], 0, 0, 0);
            acc[1] = __builtin_amdgcn_mfma_f32_16x16x32_f16(vfA1, pfrag, acc[1], 0, 0, 0);
            acc[2] = __builtin_amdgcn_mfma_f32_16x16x32_f16(vfA2, pfrag, acc[2], 0, 0, 0);
            acc[3] = __builtin_amdgcn_mfma_f32_16x16x32_f16(vfA3, pfrag, acc[3], 0, 0, 0);

            vfA0 = *(const half8*)(vkt + (size_t)8  * (16 * NROWS));
            vfA1 = *(const half8*)(vkt + (size_t)9  * (16 * NROWS));
            vfA2 = *(const half8*)(vkt + (size_t)10 * (16 * NROWS));
            vfA3 = *(const half8*)(vkt + (size_t)11 * (16 * NROWS));
            acc[4] = __builtin_amdgcn_mfma_f32_16x16x32_f16(vfB0, pfrag, acc[4], 0, 0, 0);
            acc[5] = __builtin_amdgcn_mfma_f32_16x16x32_f16(vfB1, pfrag, acc[5], 0, 0, 0);
            acc[6] = __builtin_amdgcn_mfma_f32_16x16x32_f16(vfB2, pfrag, acc[6], 0, 0, 0);
            acc[7] = __builtin_amdgcn_mfma_f32_16x16x32_f16(vfB3, pfrag, acc[7], 0, 0, 0);

            vfB0 = *(const half8*)(vkt + (size_t)12 * (16 * NROWS));
            vfB1 = *(const half8*)(vkt + (size_t)13 * (16 * NROWS));
            vfB2 = *(const half8*)(vkt + (size_t)14 * (16 * NROWS));
            vfB3 = *(const half8*)(vkt + (size_t)15 * (16 * NROWS));
            acc[8]  = __builtin_amdgcn_mfma_f32_16x16x32_f16(vfA0, pfrag, acc[8],  0, 0, 0);
            acc[9]  = __builtin_amdgcn_mfma_f32_16x16x32_f16(vfA1, pfrag, acc[9],  0, 0, 0);
            acc[10] = __builtin_amdgcn_mfma_f32_16x16x32_f16(vfA2, pfrag, acc[10], 0, 0, 0);
            acc[11] = __builtin_amdgcn_mfma_f32_16x16x32_f16(vfA3, pfrag, acc[11], 0, 0, 0);

            acc[12] = __builtin_amdgcn_mfma_f32_16x16x32_f16(vfB0, pfrag, acc[12], 0, 0, 0);
            acc[13] = __builtin_amdgcn_mfma_f32_16x16x32_f16(vfB1, pfrag, acc[13], 0, 0, 0);
            acc[14] = __builtin_amdgcn_mfma_f32_16x16x32_f16(vfB2, pfrag, acc[14], 0, 0, 0);
            acc[15] = __builtin_amdgcn_mfma_f32_16x16x32_f16(vfB3, pfrag, acc[15], 0, 0, 0);
        }

        // single barrier per ktile: own K[kt+1] landed; Ks[kt&1] free to rewrite
        asm volatile("s_waitcnt vmcnt(0)" ::: "memory");
        __builtin_amdgcn_s_barrier();
        __builtin_amdgcn_sched_barrier(0);
    }

    l_p += __shfl_xor(l_p, 16);
    l_p += __shfl_xor(l_p, 32);
    const float inv = 1.f / l_p;
    ushort* orow = ocf + ((size_t)(b * SEQ) + q0) * (HEADS * EMBED) + h * EMBED;
#pragma unroll
    for (int dt = 0; dt < 16; ++dt) {
        const f32x4 o = acc[dt] * inv;
        uint2 P2;
        P2.x = (uint)f2h(o[0]) | ((uint)f2h(o[1]) << 16);
        P2.y = (uint)f2h(o[2]) | ((uint)f2h(o[3]) << 16);
        *(uint2*)(orow + dt * 16 + 4 * g) = P2;
    }
}

extern "C" void kernel_launch(void* const* d_in, const int* in_sizes, int n_in,
                              void* d_out, int out_size, void* d_ws, size_t ws_size,
                              hipStream_t stream) {
    const float* X  = (const float*)d_in[0];
    const float* Wq = (const float*)d_in[1];
    const float* Wk = (const float*)d_in[2];
    const float* Wv = (const float*)d_in[3];
    const float* Wo = (const float*)d_in[4];
    const float* bo = (const float*)d_in[5];

    ushort* ws16 = (ushort*)d_ws;
    ushort* qf   = ws16;                     // [8][8192][256] fp16
    ushort* kf   = ws16 +  8 * QE;           // fp16
    ushort* vtb  = ws16 + 16 * QE;           // [8][256][8192] fp16
    ushort* ocf  = ws16 + 24 * QE;           // [8192][2048] fp16
    ushort* ex   = ws16 + 32 * QE;
    ushort* Xf   = ex;                       // 2M fp16
    ushort* Wqkf = ex + 2097152;             // [4096][256] fp16
    ushort* Wvf  = ex + 2097152 + 1048576;   // [2048][256] fp16
    ushort* Wof  = ex + 2097152 + 1048576 + 524288;   // [256][2048] fp16
    float*  out  = (float*)d_out;

    convert_f16<<<4096, 256, 0, stream>>>(X, Wq, Wk, Wv, Wo, Xf, Wqkf, Wvf, Wof);

    gemm_qkvt<<<3072, 256, 0, stream>>>(Xf, Wqkf, Wvf, qf, kf, vtb);

    flash_mfma<<<1024, 256, 0, stream>>>(qf, kf, vtb, ocf);

    gemm_out_f16<<<512, 256, 0, stream>>>(ocf, Wof, bo, out);
}

// Round 17
// 131.886 us; speedup vs baseline: 1.6441x; 1.6441x over previous
//
#include <hip/hip_runtime.h>
#include <hip/hip_bf16.h>

#define EMBED 256
#define HEADS 8
#define BATCH 8
#define SEQ   1024
#define NROWS 8192

typedef __attribute__((ext_vector_type(8))) _Float16 half8;   // 8 fp16
typedef __attribute__((ext_vector_type(4))) float f32x4;
typedef unsigned int  uint;
typedef unsigned short ushort;

#define QE   ((size_t)2097152)   /* per-head elems: 8192*256 */

__device__ __forceinline__ ushort f2h(float f) {
    union { _Float16 h; ushort u; } cv; cv.h = (_Float16)f; return cv.u;
}

// ---------------------------------------------------------------------------
// K0: fp32 -> fp16 convert for X and all weights, one launch.
// ---------------------------------------------------------------------------
__global__ __launch_bounds__(256) void convert_f16(
    const float* __restrict__ X,  const float* __restrict__ Wq,
    const float* __restrict__ Wk, const float* __restrict__ Wv,
    const float* __restrict__ Wo,
    ushort* __restrict__ Xf, ushort* __restrict__ Wqkf,
    ushort* __restrict__ Wvf, ushort* __restrict__ Wof)
{
    const int blk = blockIdx.x;
    const float* src; ushort* dst; int i;
    if (blk < 2048)      { src = X;  dst = Xf;            i = blk * 256 + threadIdx.x; }
    else if (blk < 2560) { src = Wq; dst = Wqkf;          i = (blk - 2048) * 256 + threadIdx.x; }
    else if (blk < 3072) { src = Wk; dst = Wqkf + 524288; i = (blk - 2560) * 256 + threadIdx.x; }
    else if (blk < 3584) { src = Wv; dst = Wvf;           i = (blk - 3072) * 256 + threadIdx.x; }
    else                 { src = Wo; dst = Wof;           i = (blk - 3584) * 256 + threadIdx.x; }
    const float4 v = ((const float4*)src)[i];
    uint2 P;
    P.x = (uint)f2h(v.x) | ((uint)f2h(v.y) << 16);
    P.y = (uint)f2h(v.z) | ((uint)f2h(v.w) << 16);
    ((uint2*)dst)[i] = P;
}

// ---------------------------------------------------------------------------
// Single-pass fp16 MFMA GEMM core (NT): BM=BN=128, BK=64, KD=256,
// 256 threads = 4 waves (2x2), serial staging (R14-proven best).
// mode 0: q/k write; mode 1: vt write.
// ---------------------------------------------------------------------------
__device__ __forceinline__ void gemm1p_core(
    const ushort* __restrict__ Ag, const ushort* __restrict__ Bg,
    ushort* __restrict__ o0, ushort* __restrict__ o1,
    ushort* Ah, ushort* Bh, int m0, int n0, int mode)
{
    const int tid = threadIdx.x, w = tid >> 6, l = tid & 63;
    const int wr = w >> 1, wc = w & 1, g = l >> 4, c16 = l & 15;
    const int sr = l >> 3, sb = l & 7;

    f32x4 acc[4][4];
#pragma unroll
    for (int mi = 0; mi < 4; ++mi)
#pragma unroll
        for (int ni = 0; ni < 4; ++ni) acc[mi][ni] = (f32x4){0.f, 0.f, 0.f, 0.f};

    for (int k0 = 0; k0 < 256; k0 += 64) {
        __syncthreads();
#pragma unroll
        for (int j = 0; j < 4; ++j) {
            const int rb = w * 32 + j * 8;
            const int r  = rb + sr;
            const size_t srcA = (size_t)(m0 + r) * 256 + k0 + ((sb ^ (r & 7)) * 8);
            __builtin_amdgcn_global_load_lds(Ag + srcA, &Ah[rb * 64], 16, 0, 0);
            const size_t srcB = (size_t)(n0 + r) * 256 + k0 + ((sb ^ (r & 7)) * 8);
            __builtin_amdgcn_global_load_lds(Bg + srcB, &Bh[rb * 64], 16, 0, 0);
        }
        asm volatile("s_waitcnt vmcnt(0)" ::: "memory");
        __syncthreads();

#pragma unroll
        for (int kh = 0; kh < 2; ++kh) {
            const int bsel = ((kh << 2) | g) ^ (c16 & 7);
            half8 af[4], bf[4];
#pragma unroll
            for (int mi = 0; mi < 4; ++mi)
                af[mi] = *(const half8*)&Ah[(wr * 64 + mi * 16 + c16) * 64 + bsel * 8];
#pragma unroll
            for (int ni = 0; ni < 4; ++ni)
                bf[ni] = *(const half8*)&Bh[(wc * 64 + ni * 16 + c16) * 64 + bsel * 8];
#pragma unroll
            for (int mi = 0; mi < 4; ++mi)
#pragma unroll
                for (int ni = 0; ni < 4; ++ni)
                    acc[mi][ni] = __builtin_amdgcn_mfma_f32_16x16x32_f16(af[mi], bf[ni], acc[mi][ni], 0, 0, 0);
        }
    }

#pragma unroll
    for (int mi = 0; mi < 4; ++mi)
#pragma unroll
        for (int ni = 0; ni < 4; ++ni) {
            const int n = n0 + wc * 64 + ni * 16 + c16;
            if (mode == 0) {
                const int op = n >> 11, hh = (n >> 8) & 7, d = n & 255;
                ushort* tq = (op ? o1 : o0) + (size_t)hh * QE + d;
#pragma unroll
                for (int j = 0; j < 4; ++j) {
                    const int m = m0 + wr * 64 + mi * 16 + 4 * g + j;
                    tq[(size_t)m * 256] = f2h(acc[mi][ni][j]);
                }
            } else {
#pragma unroll
                for (int j = 0; j < 4; ++j) {
                    const int m = m0 + wr * 64 + mi * 16 + 4 * g + j;
                    o0[(size_t)m * NROWS + n] = f2h(acc[mi][ni][j]);
                }
            }
        }
}

// Merged QK + VT projection launch: bid<2048 -> qk GEMM, else vt GEMM.
// vt part: n is the XCD-partitioned dim (X footprint 512KB + Wv 1MB per XCD).
__global__ __launch_bounds__(256) void gemm_qkvt(
    const ushort* __restrict__ Xf,
    const ushort* __restrict__ Wqkf, const ushort* __restrict__ Wvf,
    ushort* __restrict__ qf, ushort* __restrict__ kf, ushort* __restrict__ vtb)
{
    __shared__ __align__(16) ushort Ah[128 * 64];
    __shared__ __align__(16) ushort Bh[128 * 64];
    const int bid = blockIdx.x;
    if (bid < 2048) {
        const int wg = (bid & 7) * 256 + (bid >> 3);
        gemm1p_core(Xf, Wqkf, qf, kf, Ah, Bh, (wg >> 5) * 128, (wg & 31) * 128, 0);
    } else {
        const int b2 = bid - 2048;
        const int wg = (b2 & 7) * 128 + (b2 >> 3);
        gemm1p_core(Wvf, Xf, vtb, nullptr, Ah, Bh, (wg & 15) * 128, (wg >> 4) * 128, 1);
    }
}

// ---------------------------------------------------------------------------
// K3: fp16 output projection, BM=64 x BN=64 -> 512 blocks, serial staging.
// out[8192][256] = ocf x Wof^T + bo. LDS 16KB.
// ---------------------------------------------------------------------------
__global__ __launch_bounds__(256) void gemm_out_f16(
    const ushort* __restrict__ A, const ushort* __restrict__ Bw,
    const float* __restrict__ bias, float* __restrict__ fo)
{
    __shared__ __align__(16) ushort Ah[64 * 64];
    __shared__ __align__(16) ushort Bh[64 * 64];

    const int wg = (blockIdx.x & 7) * 64 + (blockIdx.x >> 3);
    const int m0 = (wg >> 2) * 64;
    const int n0 = (wg & 3) * 64;

    const int tid = threadIdx.x, w = tid >> 6, l = tid & 63;
    const int wr = w >> 1, wc = w & 1, g = l >> 4, c16 = l & 15;
    const int sr = l >> 3, sb = l & 7;

    f32x4 acc[2][2];
#pragma unroll
    for (int mi = 0; mi < 2; ++mi)
#pragma unroll
        for (int ni = 0; ni < 2; ++ni) acc[mi][ni] = (f32x4){0.f, 0.f, 0.f, 0.f};

    for (int k0 = 0; k0 < 2048; k0 += 64) {
        __syncthreads();
#pragma unroll
        for (int j = 0; j < 2; ++j) {
            const int rb = w * 16 + j * 8;
            const int r  = rb + sr;
            const size_t srcA = (size_t)(m0 + r) * 2048 + k0 + ((sb ^ (r & 7)) * 8);
            __builtin_amdgcn_global_load_lds(A + srcA, &Ah[rb * 64], 16, 0, 0);
            const size_t srcB = (size_t)(n0 + r) * 2048 + k0 + ((sb ^ (r & 7)) * 8);
            __builtin_amdgcn_global_load_lds(Bw + srcB, &Bh[rb * 64], 16, 0, 0);
        }
        asm volatile("s_waitcnt vmcnt(0)" ::: "memory");
        __syncthreads();

#pragma unroll
        for (int kh = 0; kh < 2; ++kh) {
            const int bsel = ((kh << 2) | g) ^ (c16 & 7);
            half8 af[2], bf[2];
#pragma unroll
            for (int mi = 0; mi < 2; ++mi)
                af[mi] = *(const half8*)&Ah[(wr * 32 + mi * 16 + c16) * 64 + bsel * 8];
#pragma unroll
            for (int ni = 0; ni < 2; ++ni)
                bf[ni] = *(const half8*)&Bh[(wc * 32 + ni * 16 + c16) * 64 + bsel * 8];
#pragma unroll
            for (int mi = 0; mi < 2; ++mi)
#pragma unroll
                for (int ni = 0; ni < 2; ++ni)
                    acc[mi][ni] = __builtin_amdgcn_mfma_f32_16x16x32_f16(af[mi], bf[ni], acc[mi][ni], 0, 0, 0);
        }
    }

#pragma unroll
    for (int mi = 0; mi < 2; ++mi)
#pragma unroll
        for (int ni = 0; ni < 2; ++ni) {
            const int n = n0 + wc * 32 + ni * 16 + c16;
            const float bb = bias[n];
#pragma unroll
            for (int j = 0; j < 4; ++j) {
                const int m = m0 + wr * 32 + mi * 16 + 4 * g + j;
                fo[(size_t)m * 256 + n] = acc[mi][ni][j] + bb;
            }
        }
}

// ---------------------------------------------------------------------------
// K2: fp16 MFMA flash attention — R12 structure EXACTLY (measured 76.6-77.2us;
// best of 9 flash variants tried R6-R16). 16 q-rows/wave, 4 waves, LDS 52KB
// (K dbuf 32K + VT 16K + P 4K), 1024 blocks heavy-first, hb pinned per XCD,
// counted vmcnt (barrier1 waits own VT vmcnt(4); K[kt+1] stays in flight).
// Rejected by A/B: setprio (+3us), 8-wave blocks (+95us), V-direct (+85us),
// 32q/wave @2blk/CU (+70us), direct-global-everything (+110us).
// ---------------------------------------------------------------------------
__global__ __launch_bounds__(256, 3) void flash_mfma(
    const ushort* __restrict__ qf, const ushort* __restrict__ kf,
    const ushort* __restrict__ vt, ushort* __restrict__ ocf)
{
    __shared__ __align__(16) ushort Ks[2][32 * 256];
    __shared__ __align__(16) ushort VTs[256 * 32];
    __shared__ __align__(16) ushort Pls[4][512];

    const int bid = blockIdx.x;
    const int idx = bid >> 3;
    const int hb  = (bid & 7) * 8 + (idx & 7);   // same-XCD hb groups
    const int qst = 15 - (idx >> 3);             // heavy-first
    const int h = hb >> 3, b = hb & 7;

    const int tid = threadIdx.x;
    const int w = tid >> 6, l = tid & 63;
    const int g = l >> 4, c16 = l & 15;
    const size_t qk_base = (size_t)h * QE + (size_t)b * (SEQ * EMBED);
    const size_t vt_base = (size_t)h * QE + (size_t)b * SEQ;

    const int psw = (c16 >> 1) & 3;
    const int rsw = c16 & 7;
    const int qw0 = qst * 64 + w * 16;
    const int q0 = qw0 + c16;

    half8 qfr[8];
    {
        const ushort* qr = qf + qk_base + (size_t)q0 * EMBED + g * 8;
#pragma unroll
        for (int kc = 0; kc < 8; ++kc)
            qfr[kc] = *(const half8*)(qr + kc * 32);
    }

    const ushort* kbase = kf + qk_base;
    const ushort* vbase = vt + vt_base;
    const int krow_l = l >> 5, kblk = l & 31;
    const int vd_l = l >> 2,  vblk = l & 3;
    uint koff[4], voff[4];
#pragma unroll
    for (int j = 0; j < 4; ++j) {
        const int row = 8 * w + 2 * j + krow_l;
        koff[j] = (uint)(row * EMBED + ((kblk ^ (row & 7)) * 8));
        const int d = w * 64 + j * 16 + vd_l;
        const int phi = ((d >> 1) ^ (d >> 3)) & 3;
        voff[j] = (uint)(d * NROWS + ((vblk ^ phi) * 8));
    }

    f32x4 acc[16];
#pragma unroll
    for (int dt = 0; dt < 16; ++dt) acc[dt] = (f32x4){0.f, 0.f, 0.f, 0.f};
    float m_r = -1e30f, l_p = 0.f;

    char* pw = (char*)&Pls[w][0];
    const int nkt = 2 * qst + 2;

    // prologue: stage K[0]
#pragma unroll
    for (int j = 0; j < 4; ++j)
        __builtin_amdgcn_global_load_lds(kbase + koff[j], &Ks[0][(8 * w + 2 * j) * 256], 16, 0, 0);
    asm volatile("s_waitcnt vmcnt(0)" ::: "memory");
    __builtin_amdgcn_s_barrier();
    __builtin_amdgcn_sched_barrier(0);

    for (int kt = 0; kt < nkt; ++kt) {
        // issue VT[kt] FIRST (oldest in queue -> covered by vmcnt(4)),
        // then K[kt+1] (covered by barrier2's vmcnt(0)).
#pragma unroll
        for (int j = 0; j < 4; ++j)
            __builtin_amdgcn_global_load_lds(vbase + voff[j] + kt * 32,
                                             &VTs[(w * 64 + j * 16) * 32], 16, 0, 0);
        const bool havek = (kt + 1 < nkt);
        if (havek) {
            const ushort* kb = kbase + (size_t)(kt + 1) * (32 * EMBED);
#pragma unroll
            for (int j = 0; j < 4; ++j)
                __builtin_amdgcn_global_load_lds(kb + koff[j],
                                                 &Ks[(kt + 1) & 1][(8 * w + 2 * j) * 256], 16, 0, 0);
        }

        const bool active = (kt * 32 <= qw0 + 15);
        if (active) {
            // ---- QK^T on K[kt] (already complete from previous barrier2) ----
            const ushort* Kb = &Ks[kt & 1][0];
            f32x4 s0 = (f32x4){0.f, 0.f, 0.f, 0.f};
            f32x4 s1 = (f32x4){0.f, 0.f, 0.f, 0.f};
#pragma unroll
            for (int kc = 0; kc < 8; ++kc) {
                const int blk = ((kc * 4 + g) ^ rsw) * 8;
                const half8 a0 = *(const half8*)&Kb[c16 * 256 + blk];
                const half8 a1 = *(const half8*)&Kb[(c16 + 16) * 256 + blk];
                s0 = __builtin_amdgcn_mfma_f32_16x16x32_f16(a0, qfr[kc], s0, 0, 0, 0);
                s1 = __builtin_amdgcn_mfma_f32_16x16x32_f16(a1, qfr[kc], s1, 0, 0, 0);
            }
            const int k0b = kt * 32 + 4 * g;
            float p0[4], p1[4];
            float pm = -1e30f;
#pragma unroll
            for (int r = 0; r < 4; ++r) {
                p0[r] = (k0b + r      > q0) ? -1e30f : s0[r];
                p1[r] = (k0b + 16 + r > q0) ? -1e30f : s1[r];
                pm = fmaxf(pm, fmaxf(p0[r], p1[r]));
            }
            if (__any(pm > m_r + 8.f)) {
                float gm = fmaxf(pm, __shfl_xor(pm, 16));
                gm = fmaxf(gm, __shfl_xor(gm, 32));
                const float mn = fmaxf(m_r, gm);
                const float sc = __expf(m_r - mn);
                l_p *= sc;
#pragma unroll
                for (int dt = 0; dt < 16; ++dt) acc[dt] *= sc;
                m_r = mn;
            }
#pragma unroll
            for (int r = 0; r < 4; ++r) {
                p0[r] = __expf(p0[r] - m_r);
                p1[r] = __expf(p1[r] - m_r);
                l_p += p0[r] + p1[r];
            }
#pragma unroll
            for (int t = 0; t < 2; ++t)
#pragma unroll
                for (int u = 0; u < 2; ++u) {
                    const int kk = 16 * t + 4 * g + 2 * u;
                    const int off = c16 * 64 + (((kk >> 3) ^ psw) * 16) + (kk & 7) * 2;
                    const float lo = t ? p1[2 * u] : p0[2 * u];
                    const float hi = t ? p1[2 * u + 1] : p0[2 * u + 1];
                    *(uint*)(pw + off) = (uint)f2h(lo) | ((uint)f2h(hi) << 16);
                }
        }

        // barrier1: own VT landed (K[kt+1] stays in flight when havek)
        if (havek) asm volatile("s_waitcnt vmcnt(4)" ::: "memory");
        else       asm volatile("s_waitcnt vmcnt(0)" ::: "memory");
        __builtin_amdgcn_s_barrier();
        __builtin_amdgcn_sched_barrier(0);

        if (active) {
            const half8 pfrag = *(const half8*)(pw + c16 * 64 + ((g ^ psw) * 16));
#pragma unroll
            for (int dt = 0; dt < 16; ++dt) {
                const int d = dt * 16 + c16;
                const int phi = ((d >> 1) ^ (d >> 3)) & 3;
                const half8 va = *(const half8*)&VTs[d * 32 + ((g ^ phi) * 8)];
                acc[dt] = __builtin_amdgcn_mfma_f32_16x16x32_f16(va, pfrag, acc[dt], 0, 0, 0);
            }
        }

        // barrier2: own K[kt+1] landed; VT buffer free for next iter
        asm volatile("s_waitcnt vmcnt(0)" ::: "memory");
        __builtin_amdgcn_s_barrier();
        __builtin_amdgcn_sched_barrier(0);
    }

    l_p += __shfl_xor(l_p, 16);
    l_p += __shfl_xor(l_p, 32);
    const float inv = 1.f / l_p;
    ushort* orow = ocf + ((size_t)(b * SEQ) + q0) * (HEADS * EMBED) + h * EMBED;
#pragma unroll
    for (int dt = 0; dt < 16; ++dt) {
        const f32x4 o = acc[dt] * inv;
        uint2 P2;
        P2.x = (uint)f2h(o[0]) | ((uint)f2h(o[1]) << 16);
        P2.y = (uint)f2h(o[2]) | ((uint)f2h(o[3]) << 16);
        *(uint2*)(orow + dt * 16 + 4 * g) = P2;
    }
}

extern "C" void kernel_launch(void* const* d_in, const int* in_sizes, int n_in,
                              void* d_out, int out_size, void* d_ws, size_t ws_size,
                              hipStream_t stream) {
    const float* X  = (const float*)d_in[0];
    const float* Wq = (const float*)d_in[1];
    const float* Wk = (const float*)d_in[2];
    const float* Wv = (const float*)d_in[3];
    const float* Wo = (const float*)d_in[4];
    const float* bo = (const float*)d_in[5];

    ushort* ws16 = (ushort*)d_ws;
    ushort* qf   = ws16;                     // [8][8192][256] fp16
    ushort* kf   = ws16 +  8 * QE;           // fp16
    ushort* vtb  = ws16 + 16 * QE;           // [8][256][8192] fp16
    ushort* ocf  = ws16 + 24 * QE;           // [8192][2048] fp16
    ushort* ex   = ws16 + 32 * QE;
    ushort* Xf   = ex;                       // 2M fp16
    ushort* Wqkf = ex + 2097152;             // [4096][256] fp16
    ushort* Wvf  = ex + 2097152 + 1048576;   // [2048][256] fp16
    ushort* Wof  = ex + 2097152 + 1048576 + 524288;   // [256][2048] fp16
    float*  out  = (float*)d_out;

    convert_f16<<<4096, 256, 0, stream>>>(X, Wq, Wk, Wv, Wo, Xf, Wqkf, Wvf, Wof);

    gemm_qkvt<<<3072, 256, 0, stream>>>(Xf, Wqkf, Wvf, qf, kf, vtb);

    flash_mfma<<<1024, 256, 0, stream>>>(qf, kf, vtb, ocf);

    gemm_out_f16<<<512, 256, 0, stream>>>(ocf, Wof, bo, out);
}